// Round 4
// baseline (825.333 us; speedup 1.0000x reference)
//
#include <hip/hip_runtime.h>

#define LAMBDA_INIT 0.78360576653162448f

typedef __attribute__((ext_vector_type(8))) short short8;
typedef __attribute__((ext_vector_type(4))) float f32x4;

__device__ __forceinline__ unsigned short f2bf(float f) {
  unsigned int u; __builtin_memcpy(&u, &f, 4);
  u += 0x7fffu + ((u >> 16) & 1u);
  return (unsigned short)(u >> 16);
}
__device__ __forceinline__ short8 cvt8(float4 a, float4 b) {
  short8 s;
  s[0] = (short)f2bf(a.x); s[1] = (short)f2bf(a.y);
  s[2] = (short)f2bf(a.z); s[3] = (short)f2bf(a.w);
  s[4] = (short)f2bf(b.x); s[5] = (short)f2bf(b.y);
  s[6] = (short)f2bf(b.z); s[7] = (short)f2bf(b.w);
  return s;
}

// C[m,n] = sum_k A[m,k]*B[n,k]. A: f32 (AF32) or bf16; B: f32; internal bf16 MFMA.
// C: f32 (CF32) or bf16; TRANSV (bf16 only): scatter to Vt[(m>>11)*1024+n][2048]
// at col (m&2047), i.e. (b, hkv*128+d, s) so attention reads V with s fastest.
template<bool AF32, bool CF32, bool TRANSV>
__global__ __launch_bounds__(256, 2)
void gemm_bt(const void* __restrict__ Ap, const float* __restrict__ Bp,
             void* __restrict__ Cp, int M, int N, int K) {
  __shared__ __align__(16) unsigned short As[128 * 72];  // +8 pad breaks bank conflicts
  __shared__ __align__(16) unsigned short Bs[128 * 72];
  const int t = threadIdx.x;
  const int wave = t >> 6, lane = t & 63;
  const int l15 = lane & 15, l4 = lane >> 4;
  const int wm = (wave >> 1) * 64, wn = (wave & 1) * 64;
  const int m0 = blockIdx.y * 128, n0 = blockIdx.x * 128;
  const int crow = t >> 3;          // 0..31
  const int ccol = (t & 7) * 8;     // element offset 0..56
  const float* Agf = (const float*)Ap + (size_t)m0 * K;
  const unsigned short* Agh = (const unsigned short*)Ap + (size_t)m0 * K;
  const float* Bg = Bp + (size_t)n0 * K;

  const f32x4 fzero = {0.f, 0.f, 0.f, 0.f};
  f32x4 acc[4][4];
#pragma unroll
  for (int i = 0; i < 4; i++)
#pragma unroll
    for (int j = 0; j < 4; j++) acc[i][j] = fzero;

  float4 raf[4][2]; int4 rah[4]; float4 rbf[4][2];
#pragma unroll
  for (int i = 0; i < 4; i++) {
    const int row = crow + 32 * i;
    if (AF32) {
      raf[i][0] = *(const float4*)(Agf + (size_t)row * K + ccol);
      raf[i][1] = *(const float4*)(Agf + (size_t)row * K + ccol + 4);
    } else {
      rah[i] = *(const int4*)(Agh + (size_t)row * K + ccol);
    }
    rbf[i][0] = *(const float4*)(Bg + (size_t)row * K + ccol);
    rbf[i][1] = *(const float4*)(Bg + (size_t)row * K + ccol + 4);
  }
  const int NT = K >> 6;
  for (int kt = 0; kt < NT; ++kt) {
    __syncthreads();
#pragma unroll
    for (int i = 0; i < 4; i++) {
      const int row = crow + 32 * i;
      if (AF32)
        *(short8*)(&As[row * 72 + ccol]) = cvt8(raf[i][0], raf[i][1]);
      else
        *(int4*)(&As[row * 72 + ccol]) = rah[i];
      *(short8*)(&Bs[row * 72 + ccol]) = cvt8(rbf[i][0], rbf[i][1]);
    }
    __syncthreads();
    if (kt + 1 < NT) {
      const int k0 = (kt + 1) << 6;
#pragma unroll
      for (int i = 0; i < 4; i++) {
        const int row = crow + 32 * i;
        if (AF32) {
          raf[i][0] = *(const float4*)(Agf + (size_t)row * K + k0 + ccol);
          raf[i][1] = *(const float4*)(Agf + (size_t)row * K + k0 + ccol + 4);
        } else {
          rah[i] = *(const int4*)(Agh + (size_t)row * K + k0 + ccol);
        }
        rbf[i][0] = *(const float4*)(Bg + (size_t)row * K + k0 + ccol);
        rbf[i][1] = *(const float4*)(Bg + (size_t)row * K + k0 + ccol + 4);
      }
    }
#pragma unroll
    for (int ks = 0; ks < 2; ++ks) {
      short8 af[4], bfr[4];
#pragma unroll
      for (int mi = 0; mi < 4; mi++)
        af[mi] = *(const short8*)(&As[(wm + mi * 16 + l15) * 72 + ks * 32 + l4 * 8]);
#pragma unroll
      for (int ni = 0; ni < 4; ni++)
        bfr[ni] = *(const short8*)(&Bs[(wn + ni * 16 + l15) * 72 + ks * 32 + l4 * 8]);
#pragma unroll
      for (int mi = 0; mi < 4; mi++)
#pragma unroll
        for (int ni = 0; ni < 4; ni++)
          acc[mi][ni] = __builtin_amdgcn_mfma_f32_16x16x32_bf16(af[mi], bfr[ni], acc[mi][ni], 0, 0, 0);
    }
  }
#pragma unroll
  for (int mi = 0; mi < 4; mi++)
#pragma unroll
    for (int ni = 0; ni < 4; ni++)
#pragma unroll
      for (int r = 0; r < 4; r++) {
        const int m = m0 + wm + mi * 16 + l4 * 4 + r;
        const int n = n0 + wn + ni * 16 + l15;
        const float fv = acc[mi][ni][r];
        if (CF32) {
          ((float*)Cp)[(size_t)m * N + n] = fv;
        } else if (TRANSV) {
          ((unsigned short*)Cp)[((size_t)((m >> 11) * 1024 + n)) * 2048 + (m & 2047)] = f2bf(fv);
        } else {
          ((unsigned short*)Cp)[(size_t)m * N + n] = f2bf(fv);
        }
      }
}

// Interleaved rotary, in-place on bf16 buffer. cos/sin are f32 (S,32).
__global__ void rope_kernel(unsigned short* __restrict__ buf,
                            const float* __restrict__ cosb,
                            const float* __restrict__ sinb,
                            int ppt_shift, int row_len, int npairs) {
  const int idx = blockIdx.x * 256 + threadIdx.x;
  if (idx >= npairs) return;
  const int tok = idx >> ppt_shift;
  const int rem = idx & ((1 << ppt_shift) - 1);
  const int head = rem >> 5, j = rem & 31;
  const int s = tok & 2047;
  const size_t base = (size_t)tok * row_len + head * 64 + 2 * j;
  const unsigned int pair = *(const unsigned int*)(buf + base);
  unsigned int u1 = (pair & 0xffffu) << 16, u2 = (pair >> 16) << 16;
  float x1, x2; __builtin_memcpy(&x1, &u1, 4); __builtin_memcpy(&x2, &u2, 4);
  const float c = cosb[s * 32 + j];
  const float sn = sinb[s * 32 + j];
  const float o1 = x1 * c - x2 * sn;
  const float o2 = x1 * sn + x2 * c;
  const unsigned int outp = (unsigned int)f2bf(o1) | ((unsigned int)f2bf(o2) << 16);
  *(unsigned int*)(buf + base) = outp;
}

// Fused differential flash attention + diff + RMSNorm epilogue.
// Block = (q-tile of 64 rows, b*16+h). 4 waves, each owns 16 q-rows.
__global__ __launch_bounds__(256, 2)
void attn_kernel(const unsigned short* __restrict__ Q,
                 const unsigned short* __restrict__ Kb,
                 const unsigned short* __restrict__ Vt,
                 unsigned short* __restrict__ Ab,
                 const float* __restrict__ lq1,
                 const float* __restrict__ lk1,
                 const float* __restrict__ lq2,
                 const float* __restrict__ lk2,
                 const float* __restrict__ wsub) {
  const int qi = blockIdx.x;                 // 0..31
  const int bh = blockIdx.y;                 // b*16 + h
  const int b = bh >> 4, h = bh & 15, hk = h >> 1;
  const int q0 = qi * 64;
  __shared__ __align__(16) unsigned short Ks[2][64 * 72];  // K tiles per component
  __shared__ __align__(16) unsigned short Vs[128 * 72];    // V^T tile: rows d, cols s
  __shared__ __align__(16) unsigned short Ps[2][64 * 72];  // P tiles (also Q staging)
  const int t = threadIdx.x;
  const int wave = t >> 6, lane = t & 63;
  const int l15 = lane & 15, l4 = lane >> 4;
  const int crow = t >> 3, ccol = (t & 7) * 8;

  float s1 = 0.f, s2 = 0.f;
  for (int i = 0; i < 64; i++) {
    s1 += lq1[i] * lk1[i];
    s2 += lq2[i] * lk2[i];
  }
  const float lam = __expf(s1) - __expf(s2) + LAMBDA_INIT;

  // Stage both Q components into Ps (overwritten only after 2 more barriers).
#pragma unroll
  for (int c = 0; c < 2; c++) {
    const unsigned short* Qg = Q + ((size_t)(b * 2048 + q0)) * 2048 + (2 * h + c) * 64;
#pragma unroll
    for (int i = 0; i < 2; i++) {
      const int row = crow + 32 * i;
      *(int4*)(&Ps[c][row * 72 + ccol]) = *(const int4*)(Qg + (size_t)row * 2048 + ccol);
    }
  }
  __syncthreads();
  short8 qf[2][2];
#pragma unroll
  for (int c = 0; c < 2; c++)
#pragma unroll
    for (int ks = 0; ks < 2; ks++)
      qf[c][ks] = *(const short8*)(&Ps[c][(wave * 16 + l15) * 72 + ks * 32 + l4 * 8]);

  float wv[8];
#pragma unroll
  for (int nt = 0; nt < 8; nt++) wv[nt] = wsub[nt * 16 + l15];

  const f32x4 fzero = {0.f, 0.f, 0.f, 0.f};
  f32x4 accO[2][8];
#pragma unroll
  for (int c = 0; c < 2; c++)
#pragma unroll
    for (int nt = 0; nt < 8; nt++) accO[c][nt] = fzero;
  float mrow[2][4], lrow[2][4];
#pragma unroll
  for (int c = 0; c < 2; c++)
#pragma unroll
    for (int r = 0; r < 4; r++) { mrow[c][r] = -1e9f; lrow[c][r] = 0.f; }

  for (int kt = 0; kt <= qi; ++kt) {
    const int k0 = kt * 64;
    __syncthreads();  // (A) prior-iter LDS reads (and initial qf reads) completed
#pragma unroll
    for (int c = 0; c < 2; c++) {
      const unsigned short* Kg = Kb + ((size_t)(b * 2048 + k0)) * 1024 + (2 * hk + c) * 64;
#pragma unroll
      for (int i = 0; i < 2; i++) {
        const int row = crow + 32 * i;
        *(int4*)(&Ks[c][row * 72 + ccol]) = *(const int4*)(Kg + (size_t)row * 1024 + ccol);
      }
    }
    {
      const unsigned short* Vg = Vt + ((size_t)((b * 8 + hk) * 128)) * 2048 + k0;
#pragma unroll
      for (int i = 0; i < 4; i++) {
        const int row = crow + 32 * i;  // d-row 0..127
        *(int4*)(&Vs[row * 72 + ccol]) = *(const int4*)(Vg + (size_t)row * 2048 + ccol);
      }
    }
    __syncthreads();  // (B) K/V tiles visible
    const bool diag = (kt == qi);
#pragma unroll
    for (int c = 0; c < 2; c++) {
      f32x4 sc[4];
#pragma unroll
      for (int ct = 0; ct < 4; ct++) {
        const short8 kb0 = *(const short8*)(&Ks[c][(ct * 16 + l15) * 72 + 0 + l4 * 8]);
        const short8 kb1 = *(const short8*)(&Ks[c][(ct * 16 + l15) * 72 + 32 + l4 * 8]);
        f32x4 z = fzero;
        z = __builtin_amdgcn_mfma_f32_16x16x32_bf16(qf[c][0], kb0, z, 0, 0, 0);
        z = __builtin_amdgcn_mfma_f32_16x16x32_bf16(qf[c][1], kb1, z, 0, 0, 0);
        sc[ct] = z;
      }
#pragma unroll
      for (int r = 0; r < 4; r++) {
        const int qrow = q0 + wave * 16 + l4 * 4 + r;
        float pr[4];
        float mx = -1e9f;
#pragma unroll
        for (int ct = 0; ct < 4; ct++) {
          float v = sc[ct][r] * 0.125f;  // SCALE = D^-0.5
          if (diag && (k0 + ct * 16 + l15) > qrow) v = -1e9f;
          pr[ct] = v;
          mx = fmaxf(mx, v);
        }
#pragma unroll
        for (int off = 1; off < 16; off <<= 1) mx = fmaxf(mx, __shfl_xor(mx, off, 16));
        const float mn = fmaxf(mrow[c][r], mx);
        const float alpha = __expf(mrow[c][r] - mn);
        float rs = 0.f;
#pragma unroll
        for (int ct = 0; ct < 4; ct++) {
          const float p = __expf(pr[ct] - mn);
          pr[ct] = p;
          rs += p;
        }
#pragma unroll
        for (int off = 1; off < 16; off <<= 1) rs += __shfl_xor(rs, off, 16);
        lrow[c][r] = lrow[c][r] * alpha + rs;
        mrow[c][r] = mn;
#pragma unroll
        for (int nt = 0; nt < 8; nt++) accO[c][nt][r] *= alpha;
#pragma unroll
        for (int ct = 0; ct < 4; ct++)
          Ps[c][(wave * 16 + l4 * 4 + r) * 72 + ct * 16 + l15] = f2bf(pr[ct]);
      }
    }
    __syncthreads();  // (C) P tiles visible
    short8 pf[2][2];
#pragma unroll
    for (int c = 0; c < 2; c++)
#pragma unroll
      for (int ks = 0; ks < 2; ks++)
        pf[c][ks] = *(const short8*)(&Ps[c][(wave * 16 + l15) * 72 + ks * 32 + l4 * 8]);
#pragma unroll
    for (int nt = 0; nt < 8; nt++) {
      const short8 v0 = *(const short8*)(&Vs[(nt * 16 + l15) * 72 + 0 + l4 * 8]);
      const short8 v1 = *(const short8*)(&Vs[(nt * 16 + l15) * 72 + 32 + l4 * 8]);
      accO[0][nt] = __builtin_amdgcn_mfma_f32_16x16x32_bf16(pf[0][0], v0, accO[0][nt], 0, 0, 0);
      accO[0][nt] = __builtin_amdgcn_mfma_f32_16x16x32_bf16(pf[0][1], v1, accO[0][nt], 0, 0, 0);
      accO[1][nt] = __builtin_amdgcn_mfma_f32_16x16x32_bf16(pf[1][0], v0, accO[1][nt], 0, 0, 0);
      accO[1][nt] = __builtin_amdgcn_mfma_f32_16x16x32_bf16(pf[1][1], v1, accO[1][nt], 0, 0, 0);
    }
  }

  // Epilogue: o1 - lam*o2, RMS-norm over 128, * subln_w * (1 - lambda_init).
#pragma unroll
  for (int r = 0; r < 4; r++) {
    const float i1 = 1.f / fmaxf(lrow[0][r], 1e-20f);
    const float i2 = lam / fmaxf(lrow[1][r], 1e-20f);
    float av[8], ss = 0.f;
#pragma unroll
    for (int nt = 0; nt < 8; nt++) {
      const float a = accO[0][nt][r] * i1 - accO[1][nt][r] * i2;
      av[nt] = a;
      ss += a * a;
    }
#pragma unroll
    for (int off = 1; off < 16; off <<= 1) ss += __shfl_xor(ss, off, 16);
    const float sca = rsqrtf(ss * (1.f / 128.f) + 1e-5f) * (1.f - LAMBDA_INIT);
    const int qrow = q0 + wave * 16 + l4 * 4 + r;
    unsigned short* Ao = Ab + ((size_t)(b * 2048 + qrow)) * 2048 + h * 128;
#pragma unroll
    for (int nt = 0; nt < 8; nt++)
      Ao[nt * 16 + l15] = f2bf(av[nt] * sca * wv[nt]);
  }
}

extern "C" void kernel_launch(void* const* d_in, const int* in_sizes, int n_in,
                              void* d_out, int out_size, void* d_ws, size_t ws_size,
                              hipStream_t stream) {
  const float* x    = (const float*)d_in[0];
  const float* cosb = (const float*)d_in[1];
  const float* sinb = (const float*)d_in[2];
  const float* Wq   = (const float*)d_in[3];
  const float* Wk   = (const float*)d_in[4];
  const float* Wv   = (const float*)d_in[5];
  const float* Wo   = (const float*)d_in[6];
  const float* lq1  = (const float*)d_in[7];
  const float* lk1  = (const float*)d_in[8];
  const float* lq2  = (const float*)d_in[9];
  const float* lk2  = (const float*)d_in[10];
  const float* wsub = (const float*)d_in[11];
  float* out = (float*)d_out;

  // d_out is 4096*2048 f32 = 32 MiB. Temporarily host bf16 intermediates there:
  //   K (8 MiB) | Vt (8 MiB) | Q (16 MiB). attn writes A (bf16, 16 MiB) to ws.
  //   Final GEMM reads A from ws + Wo, overwrites all of d_out with f32 C
  //   (K/Vt/Q dead by then). ws requirement: 16 MiB only.
  unsigned short* Kb  = (unsigned short*)d_out;
  unsigned short* Vtb = Kb + (size_t)4096 * 1024;
  unsigned short* Qb  = Vtb + (size_t)2 * 1024 * 2048;
  unsigned short* Ab  = (unsigned short*)d_ws;

  dim3 blk(256);
  gemm_bt<true, false, false><<<dim3(8, 32), blk, 0, stream>>>(x, Wk, Kb, 4096, 1024, 2048);
  gemm_bt<true, false, true ><<<dim3(8, 32), blk, 0, stream>>>(x, Wv, Vtb, 4096, 1024, 2048);
  gemm_bt<true, false, false><<<dim3(16, 32), blk, 0, stream>>>(x, Wq, Qb, 4096, 2048, 2048);
  rope_kernel<<<4194304 / 256, blk, 0, stream>>>(Qb, cosb, sinb, 10, 2048, 4194304);
  rope_kernel<<<2097152 / 256, blk, 0, stream>>>(Kb, cosb, sinb, 9, 1024, 2097152);
  attn_kernel<<<dim3(32, 32), blk, 0, stream>>>(Qb, Kb, Vtb, Ab, lq1, lk1, lq2, lk2, wsub);
  gemm_bt<false, true, false><<<dim3(16, 32), blk, 0, stream>>>(Ab, Wo, out, 4096, 2048, 2048);
}

// Round 5
// 618.491 us; speedup vs baseline: 1.3344x; 1.3344x over previous
//
#include <hip/hip_runtime.h>

#define LAMBDA_INIT 0.78360576653162448f

typedef __attribute__((ext_vector_type(8))) short short8;
typedef __attribute__((ext_vector_type(4))) float f32x4;

__device__ __forceinline__ unsigned short f2bf(float f) {
  unsigned int u; __builtin_memcpy(&u, &f, 4);
  u += 0x7fffu + ((u >> 16) & 1u);
  return (unsigned short)(u >> 16);
}
__device__ __forceinline__ short8 cvt8(float4 a, float4 b) {
  short8 s;
  s[0] = (short)f2bf(a.x); s[1] = (short)f2bf(a.y);
  s[2] = (short)f2bf(a.z); s[3] = (short)f2bf(a.w);
  s[4] = (short)f2bf(b.x); s[5] = (short)f2bf(b.y);
  s[6] = (short)f2bf(b.z); s[7] = (short)f2bf(b.w);
  return s;
}

// C[m,n] = sum_k A[m,k]*B[n,k]. A: f32 (AF32) or bf16; B: f32; internal bf16 MFMA.
// C: f32 (CF32) or bf16; TRANSV (bf16 only): scatter to Vt[(m>>11)*1024+n][2048]
// at col (m&2047), i.e. (b, hkv*128+d, s) so attention reads V with s fastest.
template<bool AF32, bool CF32, bool TRANSV>
__global__ __launch_bounds__(256, 2)
void gemm_bt(const void* __restrict__ Ap, const float* __restrict__ Bp,
             void* __restrict__ Cp, int M, int N, int K) {
  __shared__ __align__(16) unsigned short As[128 * 72];  // +8 pad breaks bank conflicts
  __shared__ __align__(16) unsigned short Bs[128 * 72];
  const int t = threadIdx.x;
  const int wave = t >> 6, lane = t & 63;
  const int l15 = lane & 15, l4 = lane >> 4;
  const int wm = (wave >> 1) * 64, wn = (wave & 1) * 64;
  const int m0 = blockIdx.y * 128, n0 = blockIdx.x * 128;
  const int crow = t >> 3;          // 0..31
  const int ccol = (t & 7) * 8;     // element offset 0..56
  const float* Agf = (const float*)Ap + (size_t)m0 * K;
  const unsigned short* Agh = (const unsigned short*)Ap + (size_t)m0 * K;
  const float* Bg = Bp + (size_t)n0 * K;

  const f32x4 fzero = {0.f, 0.f, 0.f, 0.f};
  f32x4 acc[4][4];
#pragma unroll
  for (int i = 0; i < 4; i++)
#pragma unroll
    for (int j = 0; j < 4; j++) acc[i][j] = fzero;

  float4 raf[4][2]; int4 rah[4]; float4 rbf[4][2];
#pragma unroll
  for (int i = 0; i < 4; i++) {
    const int row = crow + 32 * i;
    if (AF32) {
      raf[i][0] = *(const float4*)(Agf + (size_t)row * K + ccol);
      raf[i][1] = *(const float4*)(Agf + (size_t)row * K + ccol + 4);
    } else {
      rah[i] = *(const int4*)(Agh + (size_t)row * K + ccol);
    }
    rbf[i][0] = *(const float4*)(Bg + (size_t)row * K + ccol);
    rbf[i][1] = *(const float4*)(Bg + (size_t)row * K + ccol + 4);
  }
  const int NT = K >> 6;
  for (int kt = 0; kt < NT; ++kt) {
    __syncthreads();
#pragma unroll
    for (int i = 0; i < 4; i++) {
      const int row = crow + 32 * i;
      if (AF32)
        *(short8*)(&As[row * 72 + ccol]) = cvt8(raf[i][0], raf[i][1]);
      else
        *(int4*)(&As[row * 72 + ccol]) = rah[i];
      *(short8*)(&Bs[row * 72 + ccol]) = cvt8(rbf[i][0], rbf[i][1]);
    }
    __syncthreads();
    if (kt + 1 < NT) {
      const int k0 = (kt + 1) << 6;
#pragma unroll
      for (int i = 0; i < 4; i++) {
        const int row = crow + 32 * i;
        if (AF32) {
          raf[i][0] = *(const float4*)(Agf + (size_t)row * K + k0 + ccol);
          raf[i][1] = *(const float4*)(Agf + (size_t)row * K + k0 + ccol + 4);
        } else {
          rah[i] = *(const int4*)(Agh + (size_t)row * K + k0 + ccol);
        }
        rbf[i][0] = *(const float4*)(Bg + (size_t)row * K + k0 + ccol);
        rbf[i][1] = *(const float4*)(Bg + (size_t)row * K + k0 + ccol + 4);
      }
    }
#pragma unroll
    for (int ks = 0; ks < 2; ++ks) {
      short8 af[4], bfr[4];
#pragma unroll
      for (int mi = 0; mi < 4; mi++)
        af[mi] = *(const short8*)(&As[(wm + mi * 16 + l15) * 72 + ks * 32 + l4 * 8]);
#pragma unroll
      for (int ni = 0; ni < 4; ni++)
        bfr[ni] = *(const short8*)(&Bs[(wn + ni * 16 + l15) * 72 + ks * 32 + l4 * 8]);
#pragma unroll
      for (int mi = 0; mi < 4; mi++)
#pragma unroll
        for (int ni = 0; ni < 4; ni++)
          acc[mi][ni] = __builtin_amdgcn_mfma_f32_16x16x32_bf16(af[mi], bfr[ni], acc[mi][ni], 0, 0, 0);
    }
  }
#pragma unroll
  for (int mi = 0; mi < 4; mi++)
#pragma unroll
    for (int ni = 0; ni < 4; ni++)
#pragma unroll
      for (int r = 0; r < 4; r++) {
        const int m = m0 + wm + mi * 16 + l4 * 4 + r;
        const int n = n0 + wn + ni * 16 + l15;
        const float fv = acc[mi][ni][r];
        if (CF32) {
          ((float*)Cp)[(size_t)m * N + n] = fv;
        } else if (TRANSV) {
          ((unsigned short*)Cp)[((size_t)((m >> 11) * 1024 + n)) * 2048 + (m & 2047)] = f2bf(fv);
        } else {
          ((unsigned short*)Cp)[(size_t)m * N + n] = f2bf(fv);
        }
      }
}

// Interleaved rotary, in-place on bf16 buffer. cos/sin are f32 (S,32).
__global__ void rope_kernel(unsigned short* __restrict__ buf,
                            const float* __restrict__ cosb,
                            const float* __restrict__ sinb,
                            int ppt_shift, int row_len, int npairs) {
  const int idx = blockIdx.x * 256 + threadIdx.x;
  if (idx >= npairs) return;
  const int tok = idx >> ppt_shift;
  const int rem = idx & ((1 << ppt_shift) - 1);
  const int head = rem >> 5, j = rem & 31;
  const int s = tok & 2047;
  const size_t base = (size_t)tok * row_len + head * 64 + 2 * j;
  const unsigned int pair = *(const unsigned int*)(buf + base);
  unsigned int u1 = (pair & 0xffffu) << 16, u2 = (pair >> 16) << 16;
  float x1, x2; __builtin_memcpy(&x1, &u1, 4); __builtin_memcpy(&x2, &u2, 4);
  const float c = cosb[s * 32 + j];
  const float sn = sinb[s * 32 + j];
  const float o1 = x1 * c - x2 * sn;
  const float o2 = x1 * sn + x2 * c;
  const unsigned int outp = (unsigned int)f2bf(o1) | ((unsigned int)f2bf(o2) << 16);
  *(unsigned int*)(buf + base) = outp;
}

// Fused differential flash attention + diff + RMSNorm epilogue.
// Block pi handles q-tiles {pi, 31-pi} => exactly 33 kt-iterations per block
// (uniform load). 4 waves, each owns 16 q-rows of the active tile.
// K/V tiles are register-prefetched (global latency overlaps compute);
// 2 barriers per kt. P round-trip through LDS is wave-local (no barrier).
__global__ __launch_bounds__(256, 2)
void attn_kernel(const unsigned short* __restrict__ Q,
                 const unsigned short* __restrict__ Kb,
                 const unsigned short* __restrict__ Vt,
                 unsigned short* __restrict__ Ab,
                 const float* __restrict__ lq1,
                 const float* __restrict__ lk1,
                 const float* __restrict__ lq2,
                 const float* __restrict__ lk2,
                 const float* __restrict__ wsub) {
  const int pi = blockIdx.x;                 // 0..15
  const int bh = blockIdx.y;                 // b*16 + h
  const int b = bh >> 4, h = bh & 15, hk = h >> 1;
  __shared__ __align__(16) unsigned short Ks[2][64 * 72];  // K tiles per component
  __shared__ __align__(16) unsigned short Vs[128 * 72];    // V^T tile: rows d, cols s
  __shared__ __align__(16) unsigned short Ps[2][64 * 72];  // P tiles (also Q staging)
  const int t = threadIdx.x;
  const int wave = t >> 6, lane = t & 63;
  const int l15 = lane & 15, l4 = lane >> 4;
  const int crow = t >> 3, ccol = (t & 7) * 8;

  float s1 = 0.f, s2 = 0.f;
  for (int i = 0; i < 64; i++) {
    s1 += lq1[i] * lk1[i];
    s2 += lq2[i] * lk2[i];
  }
  const float lam = __expf(s1) - __expf(s2) + LAMBDA_INIT;

  float wv[8];
#pragma unroll
  for (int nt = 0; nt < 8; nt++) wv[nt] = wsub[nt * 16 + l15];

  const f32x4 fzero = {0.f, 0.f, 0.f, 0.f};
  const unsigned short* Kgb = Kb + ((size_t)(b * 2048)) * 1024 + 2 * hk * 64;
  const unsigned short* Vgb = Vt + ((size_t)((b * 8 + hk) * 128)) * 2048;

  for (int half = 0; half < 2; ++half) {
    const int qi = half ? (31 - pi) : pi;
    const int q0 = qi * 64;

    __syncthreads();  // protect Ps/Ks/Vs from previous half's (or init) reads
    // Stage both Q components into Ps.
#pragma unroll
    for (int c = 0; c < 2; c++) {
      const unsigned short* Qg = Q + ((size_t)(b * 2048 + q0)) * 2048 + (2 * h + c) * 64;
#pragma unroll
      for (int i = 0; i < 2; i++) {
        const int row = crow + 32 * i;
        *(int4*)(&Ps[c][row * 72 + ccol]) = *(const int4*)(Qg + (size_t)row * 2048 + ccol);
      }
    }
    __syncthreads();
    short8 qf[2][2];
#pragma unroll
    for (int c = 0; c < 2; c++)
#pragma unroll
      for (int ks = 0; ks < 2; ks++)
        qf[c][ks] = *(const short8*)(&Ps[c][(wave * 16 + l15) * 72 + ks * 32 + l4 * 8]);

    f32x4 accO[2][8];
#pragma unroll
    for (int c = 0; c < 2; c++)
#pragma unroll
      for (int nt = 0; nt < 8; nt++) accO[c][nt] = fzero;
    float mrow[2][4], lrow[2][4];
#pragma unroll
    for (int c = 0; c < 2; c++)
#pragma unroll
      for (int r = 0; r < 4; r++) { mrow[c][r] = -1e9f; lrow[c][r] = 0.f; }

    // Prefetch kt=0 K/V tiles into registers.
    int4 rk[2][2], rv[4];
#pragma unroll
    for (int c = 0; c < 2; c++)
#pragma unroll
      for (int i = 0; i < 2; i++)
        rk[c][i] = *(const int4*)(Kgb + (size_t)(crow + 32 * i) * 1024 + c * 64 + ccol);
#pragma unroll
    for (int i = 0; i < 4; i++)
      rv[i] = *(const int4*)(Vgb + (size_t)(crow + 32 * i) * 2048 + ccol);

    for (int kt = 0; kt <= qi; ++kt) {
      const int k0 = kt * 64;
      __syncthreads();  // (A) prior-iter LDS reads completed
#pragma unroll
      for (int c = 0; c < 2; c++)
#pragma unroll
        for (int i = 0; i < 2; i++)
          *(int4*)(&Ks[c][(crow + 32 * i) * 72 + ccol]) = rk[c][i];
#pragma unroll
      for (int i = 0; i < 4; i++)
        *(int4*)(&Vs[(crow + 32 * i) * 72 + ccol]) = rv[i];
      __syncthreads();  // (B) K/V tiles visible
      if (kt < qi) {
        const int kn = k0 + 64;
#pragma unroll
        for (int c = 0; c < 2; c++)
#pragma unroll
          for (int i = 0; i < 2; i++)
            rk[c][i] = *(const int4*)(Kgb + (size_t)(kn + crow + 32 * i) * 1024 + c * 64 + ccol);
#pragma unroll
        for (int i = 0; i < 4; i++)
          rv[i] = *(const int4*)(Vgb + (size_t)(crow + 32 * i) * 2048 + kn + ccol);
      }
      const bool diag = (kt == qi);
#pragma unroll
      for (int c = 0; c < 2; c++) {
        f32x4 sc[4];
#pragma unroll
        for (int ct = 0; ct < 4; ct++) {
          const short8 kb0 = *(const short8*)(&Ks[c][(ct * 16 + l15) * 72 + 0 + l4 * 8]);
          const short8 kb1 = *(const short8*)(&Ks[c][(ct * 16 + l15) * 72 + 32 + l4 * 8]);
          f32x4 z = fzero;
          z = __builtin_amdgcn_mfma_f32_16x16x32_bf16(qf[c][0], kb0, z, 0, 0, 0);
          z = __builtin_amdgcn_mfma_f32_16x16x32_bf16(qf[c][1], kb1, z, 0, 0, 0);
          sc[ct] = z;
        }
#pragma unroll
        for (int r = 0; r < 4; r++) {
          const int qrow = q0 + wave * 16 + l4 * 4 + r;
          float pr[4];
          float mx = -1e9f;
#pragma unroll
          for (int ct = 0; ct < 4; ct++) {
            float v = sc[ct][r] * 0.125f;  // SCALE = D^-0.5
            if (diag && (k0 + ct * 16 + l15) > qrow) v = -1e9f;
            pr[ct] = v;
            mx = fmaxf(mx, v);
          }
#pragma unroll
          for (int off = 1; off < 16; off <<= 1) mx = fmaxf(mx, __shfl_xor(mx, off, 16));
          const float mn = fmaxf(mrow[c][r], mx);
          const float alpha = __expf(mrow[c][r] - mn);
          float rs = 0.f;
#pragma unroll
          for (int ct = 0; ct < 4; ct++) {
            const float p = __expf(pr[ct] - mn);
            pr[ct] = p;
            rs += p;
          }
#pragma unroll
          for (int off = 1; off < 16; off <<= 1) rs += __shfl_xor(rs, off, 16);
          lrow[c][r] = lrow[c][r] * alpha + rs;
          mrow[c][r] = mn;
#pragma unroll
          for (int nt = 0; nt < 8; nt++) accO[c][nt][r] *= alpha;
          // Wave-local P write: wave w writes rows [16w,16w+16) only.
#pragma unroll
          for (int ct = 0; ct < 4; ct++)
            Ps[c][(wave * 16 + l4 * 4 + r) * 72 + ct * 16 + l15] = f2bf(pr[ct]);
        }
      }
      // No barrier: each wave reads back exactly the P rows it wrote.
      short8 pf[2][2];
#pragma unroll
      for (int c = 0; c < 2; c++)
#pragma unroll
        for (int ks = 0; ks < 2; ks++)
          pf[c][ks] = *(const short8*)(&Ps[c][(wave * 16 + l15) * 72 + ks * 32 + l4 * 8]);
#pragma unroll
      for (int nt = 0; nt < 8; nt++) {
        const short8 v0 = *(const short8*)(&Vs[(nt * 16 + l15) * 72 + 0 + l4 * 8]);
        const short8 v1 = *(const short8*)(&Vs[(nt * 16 + l15) * 72 + 32 + l4 * 8]);
        accO[0][nt] = __builtin_amdgcn_mfma_f32_16x16x32_bf16(pf[0][0], v0, accO[0][nt], 0, 0, 0);
        accO[0][nt] = __builtin_amdgcn_mfma_f32_16x16x32_bf16(pf[0][1], v1, accO[0][nt], 0, 0, 0);
        accO[1][nt] = __builtin_amdgcn_mfma_f32_16x16x32_bf16(pf[1][0], v0, accO[1][nt], 0, 0, 0);
        accO[1][nt] = __builtin_amdgcn_mfma_f32_16x16x32_bf16(pf[1][1], v1, accO[1][nt], 0, 0, 0);
      }
    }

    // Epilogue: o1 - lam*o2, RMS-norm over 128, * subln_w * (1 - lambda_init).
#pragma unroll
    for (int r = 0; r < 4; r++) {
      const float i1 = 1.f / fmaxf(lrow[0][r], 1e-20f);
      const float i2 = lam / fmaxf(lrow[1][r], 1e-20f);
      float av[8], ss = 0.f;
#pragma unroll
      for (int nt = 0; nt < 8; nt++) {
        const float a = accO[0][nt][r] * i1 - accO[1][nt][r] * i2;
        av[nt] = a;
        ss += a * a;
      }
#pragma unroll
      for (int off = 1; off < 16; off <<= 1) ss += __shfl_xor(ss, off, 16);
      const float sca = rsqrtf(ss * (1.f / 128.f) + 1e-5f) * (1.f - LAMBDA_INIT);
      const int qrow = q0 + wave * 16 + l4 * 4 + r;
      unsigned short* Ao = Ab + ((size_t)(b * 2048 + qrow)) * 2048 + h * 128;
#pragma unroll
      for (int nt = 0; nt < 8; nt++)
        Ao[nt * 16 + l15] = f2bf(av[nt] * sca * wv[nt]);
    }
  }
}

extern "C" void kernel_launch(void* const* d_in, const int* in_sizes, int n_in,
                              void* d_out, int out_size, void* d_ws, size_t ws_size,
                              hipStream_t stream) {
  const float* x    = (const float*)d_in[0];
  const float* cosb = (const float*)d_in[1];
  const float* sinb = (const float*)d_in[2];
  const float* Wq   = (const float*)d_in[3];
  const float* Wk   = (const float*)d_in[4];
  const float* Wv   = (const float*)d_in[5];
  const float* Wo   = (const float*)d_in[6];
  const float* lq1  = (const float*)d_in[7];
  const float* lk1  = (const float*)d_in[8];
  const float* lq2  = (const float*)d_in[9];
  const float* lk2  = (const float*)d_in[10];
  const float* wsub = (const float*)d_in[11];
  float* out = (float*)d_out;

  // d_out is 4096*2048 f32 = 32 MiB. Temporarily host bf16 intermediates there:
  //   K (8 MiB) | Vt (8 MiB) | Q (16 MiB). attn writes A (bf16, 16 MiB) to ws.
  //   Final GEMM reads A from ws + Wo, overwrites all of d_out with f32 C
  //   (K/Vt/Q dead by then). ws requirement: 16 MiB only.
  unsigned short* Kb  = (unsigned short*)d_out;
  unsigned short* Vtb = Kb + (size_t)4096 * 1024;
  unsigned short* Qb  = Vtb + (size_t)2 * 1024 * 2048;
  unsigned short* Ab  = (unsigned short*)d_ws;

  dim3 blk(256);
  gemm_bt<true, false, false><<<dim3(8, 32), blk, 0, stream>>>(x, Wk, Kb, 4096, 1024, 2048);
  gemm_bt<true, false, true ><<<dim3(8, 32), blk, 0, stream>>>(x, Wv, Vtb, 4096, 1024, 2048);
  gemm_bt<true, false, false><<<dim3(16, 32), blk, 0, stream>>>(x, Wq, Qb, 4096, 2048, 2048);
  rope_kernel<<<4194304 / 256, blk, 0, stream>>>(Qb, cosb, sinb, 10, 2048, 4194304);
  rope_kernel<<<2097152 / 256, blk, 0, stream>>>(Kb, cosb, sinb, 9, 1024, 2097152);
  attn_kernel<<<dim3(16, 32), blk, 0, stream>>>(Qb, Kb, Vtb, Ab, lq1, lk1, lq2, lk2, wsub);
  gemm_bt<false, true, false><<<dim3(16, 32), blk, 0, stream>>>(Ab, Wo, out, 4096, 2048, 2048);
}

// Round 6
// 531.426 us; speedup vs baseline: 1.5531x; 1.1638x over previous
//
#include <hip/hip_runtime.h>

#define LAMBDA_INIT 0.78360576653162448f

typedef __attribute__((ext_vector_type(8))) short short8;
typedef __attribute__((ext_vector_type(4))) float f32x4;

__device__ __forceinline__ unsigned short f2bf(float f) {
  unsigned int u; __builtin_memcpy(&u, &f, 4);
  u += 0x7fffu + ((u >> 16) & 1u);
  return (unsigned short)(u >> 16);
}
__device__ __forceinline__ short8 cvt8(float4 a, float4 b) {
  short8 s;
  s[0] = (short)f2bf(a.x); s[1] = (short)f2bf(a.y);
  s[2] = (short)f2bf(a.z); s[3] = (short)f2bf(a.w);
  s[4] = (short)f2bf(b.x); s[5] = (short)f2bf(b.y);
  s[6] = (short)f2bf(b.z); s[7] = (short)f2bf(b.w);
  return s;
}

// Async global->LDS, 16 B per lane, wave-uniform LDS base + lane*16.
#define GLOAD_LDS16(g, l)                                                     \
  __builtin_amdgcn_global_load_lds(                                           \
      (const __attribute__((address_space(1))) void*)(g),                     \
      (__attribute__((address_space(3))) void*)(l), 16, 0, 0)

// f32 -> bf16 bulk convert, 8 elems/thread.
__global__ void conv_bf16(const float* __restrict__ in,
                          unsigned short* __restrict__ outp, int n8) {
  const int i = blockIdx.x * 256 + threadIdx.x;
  if (i >= n8) return;
  const float4 a = *(const float4*)(in + (size_t)i * 8);
  const float4 b = *(const float4*)(in + (size_t)i * 8 + 4);
  *(short8*)(outp + (size_t)i * 8) = cvt8(a, b);
}

// Fused QKV projection GEMM. A = xb (bf16, 4096x2048) via global_load_lds.
// Columns n<2048: Q (+rope); 2048..3071: K (+rope); 3072..4095: V (->Vt scatter).
// B rows come from Wq/Wk/Wv (f32), staged via register prefetch + cvt.
__global__ __launch_bounds__(256, 2)
void qkv_gemm(const unsigned short* __restrict__ xb,
              const float* __restrict__ Wq, const float* __restrict__ Wk,
              const float* __restrict__ Wv, const float* __restrict__ cosb,
              const float* __restrict__ sinb,
              unsigned short* __restrict__ Qb, unsigned short* __restrict__ Kb,
              unsigned short* __restrict__ Vtb) {
  __shared__ __align__(16) unsigned short As[128 * 64];  // unpadded: global_load_lds dest
  __shared__ __align__(16) unsigned short Bs[128 * 72];  // +8 pad
  const int t = threadIdx.x;
  const int wave = t >> 6, lane = t & 63;
  const int l15 = lane & 15, l4 = lane >> 4;
  const int wm = (wave >> 1) * 64, wn = (wave & 1) * 64;
  const int m0 = blockIdx.y * 128, n0 = blockIdx.x * 128;
  const int crow = t >> 3;        // 0..31
  const int ccol = (t & 7) * 8;   // element offset 0..56
  const unsigned short* Ag = xb + (size_t)m0 * 2048;

  const float* Bg; int ntype;
  if (n0 < 2048)      { Bg = Wq + (size_t)n0 * 2048;          ntype = 0; }
  else if (n0 < 3072) { Bg = Wk + (size_t)(n0 - 2048) * 2048; ntype = 1; }
  else                { Bg = Wv + (size_t)(n0 - 3072) * 2048; ntype = 2; }

  const f32x4 fzero = {0.f, 0.f, 0.f, 0.f};
  f32x4 acc[4][4];
#pragma unroll
  for (int i = 0; i < 4; i++)
#pragma unroll
    for (int j = 0; j < 4; j++) acc[i][j] = fzero;

  float4 rbf[4][2];
#pragma unroll
  for (int i = 0; i < 4; i++) {
    rbf[i][0] = *(const float4*)(Bg + (size_t)(crow + 32 * i) * 2048 + ccol);
    rbf[i][1] = *(const float4*)(Bg + (size_t)(crow + 32 * i) * 2048 + ccol + 4);
  }
  for (int kt = 0; kt < 32; ++kt) {
    const int k0 = kt << 6;
    __syncthreads();  // prior-iter LDS reads done
#pragma unroll
    for (int j = 0; j < 4; j++)
      GLOAD_LDS16(Ag + (size_t)(j * 32 + crow) * 2048 + k0 + ccol,
                  &As[j * 2048 + wave * 512]);
#pragma unroll
    for (int i = 0; i < 4; i++)
      *(short8*)(&Bs[(crow + 32 * i) * 72 + ccol]) = cvt8(rbf[i][0], rbf[i][1]);
    __syncthreads();  // drains vmcnt(0): As + Bs visible
    if (kt + 1 < 32) {
      const int kn = k0 + 64;
#pragma unroll
      for (int i = 0; i < 4; i++) {
        rbf[i][0] = *(const float4*)(Bg + (size_t)(crow + 32 * i) * 2048 + kn + ccol);
        rbf[i][1] = *(const float4*)(Bg + (size_t)(crow + 32 * i) * 2048 + kn + ccol + 4);
      }
    }
#pragma unroll
    for (int ks = 0; ks < 2; ++ks) {
      short8 af[4], bfr[4];
#pragma unroll
      for (int mi = 0; mi < 4; mi++)
        af[mi] = *(const short8*)(&As[(wm + mi * 16 + l15) * 64 + ks * 32 + l4 * 8]);
#pragma unroll
      for (int ni = 0; ni < 4; ni++)
        bfr[ni] = *(const short8*)(&Bs[(wn + ni * 16 + l15) * 72 + ks * 32 + l4 * 8]);
#pragma unroll
      for (int mi = 0; mi < 4; mi++)
#pragma unroll
        for (int ni = 0; ni < 4; ni++)
          acc[mi][ni] = __builtin_amdgcn_mfma_f32_16x16x32_bf16(af[mi], bfr[ni], acc[mi][ni], 0, 0, 0);
    }
  }
  // Epilogue: rope (Q/K) via lane-pair shuffle, or Vt scatter (V).
#pragma unroll
  for (int mi = 0; mi < 4; mi++)
#pragma unroll
    for (int ni = 0; ni < 4; ni++)
#pragma unroll
      for (int r = 0; r < 4; r++) {
        const int m = m0 + wm + mi * 16 + l4 * 4 + r;
        const int n = n0 + wn + ni * 16 + l15;
        float fv = acc[mi][ni][r];
        if (ntype < 2) {
          const int s = m & 2047;
          const int j = (n & 63) >> 1;
          const float c = cosb[s * 32 + j];
          const float sn = sinb[s * 32 + j];
          const float p = __shfl_xor(fv, 1);
          fv = (n & 1) ? (p * sn + fv * c) : (fv * c - p * sn);
        }
        if (ntype == 0)
          Qb[(size_t)m * 2048 + n] = f2bf(fv);
        else if (ntype == 1)
          Kb[(size_t)m * 1024 + (n - 2048)] = f2bf(fv);
        else
          Vtb[((size_t)((m >> 11) * 1024 + (n - 3072))) * 2048 + (m & 2047)] = f2bf(fv);
      }
}

// O-projection: C[m,n] = sum_k A[m,k]*Wo[n,k]; A bf16 via global_load_lds,
// Wo f32 via register prefetch + cvt, C f32.
__global__ __launch_bounds__(256, 2)
void o_gemm(const unsigned short* __restrict__ Ab, const float* __restrict__ Wo,
            float* __restrict__ C) {
  __shared__ __align__(16) unsigned short As[128 * 64];
  __shared__ __align__(16) unsigned short Bs[128 * 72];
  const int t = threadIdx.x;
  const int wave = t >> 6, lane = t & 63;
  const int l15 = lane & 15, l4 = lane >> 4;
  const int wm = (wave >> 1) * 64, wn = (wave & 1) * 64;
  const int m0 = blockIdx.y * 128, n0 = blockIdx.x * 128;
  const int crow = t >> 3, ccol = (t & 7) * 8;
  const unsigned short* Ag = Ab + (size_t)m0 * 2048;
  const float* Bg = Wo + (size_t)n0 * 2048;

  const f32x4 fzero = {0.f, 0.f, 0.f, 0.f};
  f32x4 acc[4][4];
#pragma unroll
  for (int i = 0; i < 4; i++)
#pragma unroll
    for (int j = 0; j < 4; j++) acc[i][j] = fzero;

  float4 rbf[4][2];
#pragma unroll
  for (int i = 0; i < 4; i++) {
    rbf[i][0] = *(const float4*)(Bg + (size_t)(crow + 32 * i) * 2048 + ccol);
    rbf[i][1] = *(const float4*)(Bg + (size_t)(crow + 32 * i) * 2048 + ccol + 4);
  }
  for (int kt = 0; kt < 32; ++kt) {
    const int k0 = kt << 6;
    __syncthreads();
#pragma unroll
    for (int j = 0; j < 4; j++)
      GLOAD_LDS16(Ag + (size_t)(j * 32 + crow) * 2048 + k0 + ccol,
                  &As[j * 2048 + wave * 512]);
#pragma unroll
    for (int i = 0; i < 4; i++)
      *(short8*)(&Bs[(crow + 32 * i) * 72 + ccol]) = cvt8(rbf[i][0], rbf[i][1]);
    __syncthreads();
    if (kt + 1 < 32) {
      const int kn = k0 + 64;
#pragma unroll
      for (int i = 0; i < 4; i++) {
        rbf[i][0] = *(const float4*)(Bg + (size_t)(crow + 32 * i) * 2048 + kn + ccol);
        rbf[i][1] = *(const float4*)(Bg + (size_t)(crow + 32 * i) * 2048 + kn + ccol + 4);
      }
    }
#pragma unroll
    for (int ks = 0; ks < 2; ++ks) {
      short8 af[4], bfr[4];
#pragma unroll
      for (int mi = 0; mi < 4; mi++)
        af[mi] = *(const short8*)(&As[(wm + mi * 16 + l15) * 64 + ks * 32 + l4 * 8]);
#pragma unroll
      for (int ni = 0; ni < 4; ni++)
        bfr[ni] = *(const short8*)(&Bs[(wn + ni * 16 + l15) * 72 + ks * 32 + l4 * 8]);
#pragma unroll
      for (int mi = 0; mi < 4; mi++)
#pragma unroll
        for (int ni = 0; ni < 4; ni++)
          acc[mi][ni] = __builtin_amdgcn_mfma_f32_16x16x32_bf16(af[mi], bfr[ni], acc[mi][ni], 0, 0, 0);
    }
  }
#pragma unroll
  for (int mi = 0; mi < 4; mi++)
#pragma unroll
    for (int ni = 0; ni < 4; ni++)
#pragma unroll
      for (int r = 0; r < 4; r++) {
        const int m = m0 + wm + mi * 16 + l4 * 4 + r;
        const int n = n0 + wn + ni * 16 + l15;
        C[(size_t)m * 2048 + n] = acc[mi][ni][r];
      }
}

// Fused differential flash attention + diff + RMSNorm epilogue (round-5 proven).
__global__ __launch_bounds__(256, 2)
void attn_kernel(const unsigned short* __restrict__ Q,
                 const unsigned short* __restrict__ Kb,
                 const unsigned short* __restrict__ Vt,
                 unsigned short* __restrict__ Ab,
                 const float* __restrict__ lq1,
                 const float* __restrict__ lk1,
                 const float* __restrict__ lq2,
                 const float* __restrict__ lk2,
                 const float* __restrict__ wsub) {
  const int pi = blockIdx.x;                 // 0..15
  const int bh = blockIdx.y;                 // b*16 + h
  const int b = bh >> 4, h = bh & 15, hk = h >> 1;
  __shared__ __align__(16) unsigned short Ks[2][64 * 72];
  __shared__ __align__(16) unsigned short Vs[128 * 72];
  __shared__ __align__(16) unsigned short Ps[2][64 * 72];
  const int t = threadIdx.x;
  const int wave = t >> 6, lane = t & 63;
  const int l15 = lane & 15, l4 = lane >> 4;
  const int crow = t >> 3, ccol = (t & 7) * 8;

  float s1 = 0.f, s2 = 0.f;
  for (int i = 0; i < 64; i++) {
    s1 += lq1[i] * lk1[i];
    s2 += lq2[i] * lk2[i];
  }
  const float lam = __expf(s1) - __expf(s2) + LAMBDA_INIT;

  float wv[8];
#pragma unroll
  for (int nt = 0; nt < 8; nt++) wv[nt] = wsub[nt * 16 + l15];

  const f32x4 fzero = {0.f, 0.f, 0.f, 0.f};
  const unsigned short* Kgb = Kb + ((size_t)(b * 2048)) * 1024 + 2 * hk * 64;
  const unsigned short* Vgb = Vt + ((size_t)((b * 8 + hk) * 128)) * 2048;

  for (int half = 0; half < 2; ++half) {
    const int qi = half ? (31 - pi) : pi;
    const int q0 = qi * 64;

    __syncthreads();
#pragma unroll
    for (int c = 0; c < 2; c++) {
      const unsigned short* Qg = Q + ((size_t)(b * 2048 + q0)) * 2048 + (2 * h + c) * 64;
#pragma unroll
      for (int i = 0; i < 2; i++) {
        const int row = crow + 32 * i;
        *(int4*)(&Ps[c][row * 72 + ccol]) = *(const int4*)(Qg + (size_t)row * 2048 + ccol);
      }
    }
    __syncthreads();
    short8 qf[2][2];
#pragma unroll
    for (int c = 0; c < 2; c++)
#pragma unroll
      for (int ks = 0; ks < 2; ks++)
        qf[c][ks] = *(const short8*)(&Ps[c][(wave * 16 + l15) * 72 + ks * 32 + l4 * 8]);

    f32x4 accO[2][8];
#pragma unroll
    for (int c = 0; c < 2; c++)
#pragma unroll
      for (int nt = 0; nt < 8; nt++) accO[c][nt] = fzero;
    float mrow[2][4], lrow[2][4];
#pragma unroll
    for (int c = 0; c < 2; c++)
#pragma unroll
      for (int r = 0; r < 4; r++) { mrow[c][r] = -1e9f; lrow[c][r] = 0.f; }

    int4 rk[2][2], rv[4];
#pragma unroll
    for (int c = 0; c < 2; c++)
#pragma unroll
      for (int i = 0; i < 2; i++)
        rk[c][i] = *(const int4*)(Kgb + (size_t)(crow + 32 * i) * 1024 + c * 64 + ccol);
#pragma unroll
    for (int i = 0; i < 4; i++)
      rv[i] = *(const int4*)(Vgb + (size_t)(crow + 32 * i) * 2048 + ccol);

    for (int kt = 0; kt <= qi; ++kt) {
      const int k0 = kt * 64;
      __syncthreads();
#pragma unroll
      for (int c = 0; c < 2; c++)
#pragma unroll
        for (int i = 0; i < 2; i++)
          *(int4*)(&Ks[c][(crow + 32 * i) * 72 + ccol]) = rk[c][i];
#pragma unroll
      for (int i = 0; i < 4; i++)
        *(int4*)(&Vs[(crow + 32 * i) * 72 + ccol]) = rv[i];
      __syncthreads();
      if (kt < qi) {
        const int kn = k0 + 64;
#pragma unroll
        for (int c = 0; c < 2; c++)
#pragma unroll
          for (int i = 0; i < 2; i++)
            rk[c][i] = *(const int4*)(Kgb + (size_t)(kn + crow + 32 * i) * 1024 + c * 64 + ccol);
#pragma unroll
        for (int i = 0; i < 4; i++)
          rv[i] = *(const int4*)(Vgb + (size_t)(crow + 32 * i) * 2048 + kn + ccol);
      }
      const bool diag = (kt == qi);
#pragma unroll
      for (int c = 0; c < 2; c++) {
        f32x4 sc[4];
#pragma unroll
        for (int ct = 0; ct < 4; ct++) {
          const short8 kb0 = *(const short8*)(&Ks[c][(ct * 16 + l15) * 72 + 0 + l4 * 8]);
          const short8 kb1 = *(const short8*)(&Ks[c][(ct * 16 + l15) * 72 + 32 + l4 * 8]);
          f32x4 z = fzero;
          z = __builtin_amdgcn_mfma_f32_16x16x32_bf16(qf[c][0], kb0, z, 0, 0, 0);
          z = __builtin_amdgcn_mfma_f32_16x16x32_bf16(qf[c][1], kb1, z, 0, 0, 0);
          sc[ct] = z;
        }
#pragma unroll
        for (int r = 0; r < 4; r++) {
          const int qrow = q0 + wave * 16 + l4 * 4 + r;
          float pr[4];
          float mx = -1e9f;
#pragma unroll
          for (int ct = 0; ct < 4; ct++) {
            float v = sc[ct][r] * 0.125f;
            if (diag && (k0 + ct * 16 + l15) > qrow) v = -1e9f;
            pr[ct] = v;
            mx = fmaxf(mx, v);
          }
#pragma unroll
          for (int off = 1; off < 16; off <<= 1) mx = fmaxf(mx, __shfl_xor(mx, off, 16));
          const float mn = fmaxf(mrow[c][r], mx);
          const float alpha = __expf(mrow[c][r] - mn);
          float rs = 0.f;
#pragma unroll
          for (int ct = 0; ct < 4; ct++) {
            const float p = __expf(pr[ct] - mn);
            pr[ct] = p;
            rs += p;
          }
#pragma unroll
          for (int off = 1; off < 16; off <<= 1) rs += __shfl_xor(rs, off, 16);
          lrow[c][r] = lrow[c][r] * alpha + rs;
          mrow[c][r] = mn;
#pragma unroll
          for (int nt = 0; nt < 8; nt++) accO[c][nt][r] *= alpha;
#pragma unroll
          for (int ct = 0; ct < 4; ct++)
            Ps[c][(wave * 16 + l4 * 4 + r) * 72 + ct * 16 + l15] = f2bf(pr[ct]);
        }
      }
      short8 pf[2][2];
#pragma unroll
      for (int c = 0; c < 2; c++)
#pragma unroll
        for (int ks = 0; ks < 2; ks++)
          pf[c][ks] = *(const short8*)(&Ps[c][(wave * 16 + l15) * 72 + ks * 32 + l4 * 8]);
#pragma unroll
      for (int nt = 0; nt < 8; nt++) {
        const short8 v0 = *(const short8*)(&Vs[(nt * 16 + l15) * 72 + 0 + l4 * 8]);
        const short8 v1 = *(const short8*)(&Vs[(nt * 16 + l15) * 72 + 32 + l4 * 8]);
        accO[0][nt] = __builtin_amdgcn_mfma_f32_16x16x32_bf16(pf[0][0], v0, accO[0][nt], 0, 0, 0);
        accO[0][nt] = __builtin_amdgcn_mfma_f32_16x16x32_bf16(pf[0][1], v1, accO[0][nt], 0, 0, 0);
        accO[1][nt] = __builtin_amdgcn_mfma_f32_16x16x32_bf16(pf[1][0], v0, accO[1][nt], 0, 0, 0);
        accO[1][nt] = __builtin_amdgcn_mfma_f32_16x16x32_bf16(pf[1][1], v1, accO[1][nt], 0, 0, 0);
      }
    }

#pragma unroll
    for (int r = 0; r < 4; r++) {
      const float i1 = 1.f / fmaxf(lrow[0][r], 1e-20f);
      const float i2 = lam / fmaxf(lrow[1][r], 1e-20f);
      float av[8], ss = 0.f;
#pragma unroll
      for (int nt = 0; nt < 8; nt++) {
        const float a = accO[0][nt][r] * i1 - accO[1][nt][r] * i2;
        av[nt] = a;
        ss += a * a;
      }
#pragma unroll
      for (int off = 1; off < 16; off <<= 1) ss += __shfl_xor(ss, off, 16);
      const float sca = rsqrtf(ss * (1.f / 128.f) + 1e-5f) * (1.f - LAMBDA_INIT);
      const int qrow = q0 + wave * 16 + l4 * 4 + r;
      unsigned short* Ao = Ab + ((size_t)(b * 2048 + qrow)) * 2048 + h * 128;
#pragma unroll
      for (int nt = 0; nt < 8; nt++)
        Ao[nt * 16 + l15] = f2bf(av[nt] * sca * wv[nt]);
    }
  }
}

extern "C" void kernel_launch(void* const* d_in, const int* in_sizes, int n_in,
                              void* d_out, int out_size, void* d_ws, size_t ws_size,
                              hipStream_t stream) {
  const float* x    = (const float*)d_in[0];
  const float* cosb = (const float*)d_in[1];
  const float* sinb = (const float*)d_in[2];
  const float* Wq   = (const float*)d_in[3];
  const float* Wk   = (const float*)d_in[4];
  const float* Wv   = (const float*)d_in[5];
  const float* Wo   = (const float*)d_in[6];
  const float* lq1  = (const float*)d_in[7];
  const float* lk1  = (const float*)d_in[8];
  const float* lq2  = (const float*)d_in[9];
  const float* lk2  = (const float*)d_in[10];
  const float* wsub = (const float*)d_in[11];
  float* out = (float*)d_out;

  // Buffers: ws[0,16MiB) = xb (bf16 x) until QKV GEMM, then A (attn out).
  // d_out (32 MiB f32) temporarily hosts bf16 K(8) | Vt(8) | Q(16); final
  // O-GEMM reads A from ws and overwrites d_out with f32 C.
  unsigned short* XA  = (unsigned short*)d_ws;   // xb, later Ab (aliased)
  unsigned short* Kb  = (unsigned short*)d_out;
  unsigned short* Vtb = Kb + (size_t)4096 * 1024;
  unsigned short* Qb  = Vtb + (size_t)2 * 1024 * 2048;

  dim3 blk(256);
  conv_bf16<<<4096, blk, 0, stream>>>(x, XA, 1048576);
  qkv_gemm<<<dim3(32, 32), blk, 0, stream>>>(XA, Wq, Wk, Wv, cosb, sinb, Qb, Kb, Vtb);
  attn_kernel<<<dim3(16, 32), blk, 0, stream>>>(Qb, Kb, Vtb, XA, lq1, lk1, lq2, lk2, wsub);
  o_gemm<<<dim3(16, 32), blk, 0, stream>>>(XA, Wo, out);
}

// Round 7
// 430.563 us; speedup vs baseline: 1.9169x; 1.2343x over previous
//
#include <hip/hip_runtime.h>

#define LAMBDA_INIT 0.78360576653162448f

typedef __attribute__((ext_vector_type(8))) short short8;
typedef __attribute__((ext_vector_type(4))) float f32x4;

__device__ __forceinline__ unsigned short f2bf(float f) {
  unsigned int u; __builtin_memcpy(&u, &f, 4);
  u += 0x7fffu + ((u >> 16) & 1u);
  return (unsigned short)(u >> 16);
}
__device__ __forceinline__ short8 cvt8(float4 a, float4 b) {
  short8 s;
  s[0] = (short)f2bf(a.x); s[1] = (short)f2bf(a.y);
  s[2] = (short)f2bf(a.z); s[3] = (short)f2bf(a.w);
  s[4] = (short)f2bf(b.x); s[5] = (short)f2bf(b.y);
  s[6] = (short)f2bf(b.z); s[7] = (short)f2bf(b.w);
  return s;
}

// Async global->LDS, 16 B per lane, wave-uniform LDS base + lane*16.
#define GLOAD_LDS16(g, l)                                                     \
  __builtin_amdgcn_global_load_lds(                                           \
      (const __attribute__((address_space(1))) void*)(g),                     \
      (__attribute__((address_space(3))) void*)(l), 16, 0, 0)

// f32 -> bf16 bulk convert, 8 elems/thread (x only; fallback path).
__global__ void conv_bf16(const float* __restrict__ in,
                          unsigned short* __restrict__ outp, int n8) {
  const int i = blockIdx.x * 256 + threadIdx.x;
  if (i >= n8) return;
  const float4 a = *(const float4*)(in + (size_t)i * 8);
  const float4 b = *(const float4*)(in + (size_t)i * 8 + 4);
  *(short8*)(outp + (size_t)i * 8) = cvt8(a, b);
}

// Fused f32->bf16 convert of x + all four weights into ws (fast path).
// Segment boundaries are multiples of 256 => block-uniform branches.
__global__ void conv_all(const float* __restrict__ x, const float* __restrict__ wq,
                         const float* __restrict__ wk, const float* __restrict__ wv,
                         const float* __restrict__ wo, unsigned short* __restrict__ ws) {
  const int i = blockIdx.x * 256 + threadIdx.x;  // unit of 8 elems
  const float* src; size_t so; unsigned short* dst;
  if (i < 1048576)      { src = x;  so = i;           dst = ws; }
  else if (i < 1572864) { src = wq; so = i - 1048576; dst = ws + 8388608; }
  else if (i < 1835008) { src = wk; so = i - 1572864; dst = ws + 12582912; }
  else if (i < 2097152) { src = wv; so = i - 1835008; dst = ws + 14680064; }
  else                  { src = wo; so = i - 2097152; dst = ws + 16777216; }
  const float4 a = *(const float4*)(src + so * 8);
  const float4 b = *(const float4*)(src + so * 8 + 4);
  *(short8*)(dst + so * 8) = cvt8(a, b);
}

// ---------- Fast-path GEMMs: both operands bf16, staged via global_load_lds.

// Fused QKV projection. A = xb (4096x2048 bf16). n<2048: Q(+rope);
// 2048..3071: K(+rope); 3072..4095: V (Vt scatter). B = bf16 weights.
__global__ __launch_bounds__(256, 2)
void qkv_bb(const unsigned short* __restrict__ xb,
            const unsigned short* __restrict__ Wqb, const unsigned short* __restrict__ Wkb,
            const unsigned short* __restrict__ Wvb, const float* __restrict__ cosb,
            const float* __restrict__ sinb,
            unsigned short* __restrict__ Qb, unsigned short* __restrict__ Kb,
            unsigned short* __restrict__ Vtb) {
  __shared__ __align__(16) unsigned short As[128 * 64];
  __shared__ __align__(16) unsigned short Bs[128 * 64];
  const int t = threadIdx.x;
  const int wave = t >> 6, lane = t & 63;
  const int l15 = lane & 15, l4 = lane >> 4;
  const int wm = (wave >> 1) * 64, wn = (wave & 1) * 64;
  const int m0 = blockIdx.y * 128, n0 = blockIdx.x * 128;
  const int crow = t >> 3, ccol = (t & 7) * 8;
  const unsigned short* Ag = xb + (size_t)m0 * 2048;

  const unsigned short* Bgh; int ntype;
  if (n0 < 2048)      { Bgh = Wqb + (size_t)n0 * 2048;          ntype = 0; }
  else if (n0 < 3072) { Bgh = Wkb + (size_t)(n0 - 2048) * 2048; ntype = 1; }
  else                { Bgh = Wvb + (size_t)(n0 - 3072) * 2048; ntype = 2; }

  const f32x4 fzero = {0.f, 0.f, 0.f, 0.f};
  f32x4 acc[4][4];
#pragma unroll
  for (int i = 0; i < 4; i++)
#pragma unroll
    for (int j = 0; j < 4; j++) acc[i][j] = fzero;

  for (int kt = 0; kt < 32; ++kt) {
    const int k0 = kt << 6;
    __syncthreads();
#pragma unroll
    for (int j = 0; j < 4; j++) {
      GLOAD_LDS16(Ag + (size_t)(j * 32 + crow) * 2048 + k0 + ccol,
                  &As[j * 2048 + wave * 512]);
      GLOAD_LDS16(Bgh + (size_t)(j * 32 + crow) * 2048 + k0 + ccol,
                  &Bs[j * 2048 + wave * 512]);
    }
    __syncthreads();
#pragma unroll
    for (int ks = 0; ks < 2; ++ks) {
      short8 af[4], bfr[4];
#pragma unroll
      for (int mi = 0; mi < 4; mi++)
        af[mi] = *(const short8*)(&As[(wm + mi * 16 + l15) * 64 + ks * 32 + l4 * 8]);
#pragma unroll
      for (int ni = 0; ni < 4; ni++)
        bfr[ni] = *(const short8*)(&Bs[(wn + ni * 16 + l15) * 64 + ks * 32 + l4 * 8]);
#pragma unroll
      for (int mi = 0; mi < 4; mi++)
#pragma unroll
        for (int ni = 0; ni < 4; ni++)
          acc[mi][ni] = __builtin_amdgcn_mfma_f32_16x16x32_bf16(af[mi], bfr[ni], acc[mi][ni], 0, 0, 0);
    }
  }
#pragma unroll
  for (int mi = 0; mi < 4; mi++)
#pragma unroll
    for (int ni = 0; ni < 4; ni++)
#pragma unroll
      for (int r = 0; r < 4; r++) {
        const int m = m0 + wm + mi * 16 + l4 * 4 + r;
        const int n = n0 + wn + ni * 16 + l15;
        float fv = acc[mi][ni][r];
        if (ntype < 2) {
          const int s = m & 2047;
          const int j = (n & 63) >> 1;
          const float c = cosb[s * 32 + j];
          const float sn = sinb[s * 32 + j];
          const float p = __shfl_xor(fv, 1);
          fv = (n & 1) ? (p * sn + fv * c) : (fv * c - p * sn);
        }
        if (ntype == 0)
          Qb[(size_t)m * 2048 + n] = f2bf(fv);
        else if (ntype == 1)
          Kb[(size_t)m * 1024 + (n - 2048)] = f2bf(fv);
        else
          Vtb[((size_t)((m >> 11) * 1024 + (n - 3072))) * 2048 + (m & 2047)] = f2bf(fv);
      }
}

// O-projection, both operands bf16, C f32.
__global__ __launch_bounds__(256, 2)
void o_bb(const unsigned short* __restrict__ Ab, const unsigned short* __restrict__ Wob,
          float* __restrict__ C) {
  __shared__ __align__(16) unsigned short As[128 * 64];
  __shared__ __align__(16) unsigned short Bs[128 * 64];
  const int t = threadIdx.x;
  const int wave = t >> 6, lane = t & 63;
  const int l15 = lane & 15, l4 = lane >> 4;
  const int wm = (wave >> 1) * 64, wn = (wave & 1) * 64;
  const int m0 = blockIdx.y * 128, n0 = blockIdx.x * 128;
  const int crow = t >> 3, ccol = (t & 7) * 8;
  const unsigned short* Ag = Ab + (size_t)m0 * 2048;
  const unsigned short* Bgh = Wob + (size_t)n0 * 2048;

  const f32x4 fzero = {0.f, 0.f, 0.f, 0.f};
  f32x4 acc[4][4];
#pragma unroll
  for (int i = 0; i < 4; i++)
#pragma unroll
    for (int j = 0; j < 4; j++) acc[i][j] = fzero;

  for (int kt = 0; kt < 32; ++kt) {
    const int k0 = kt << 6;
    __syncthreads();
#pragma unroll
    for (int j = 0; j < 4; j++) {
      GLOAD_LDS16(Ag + (size_t)(j * 32 + crow) * 2048 + k0 + ccol,
                  &As[j * 2048 + wave * 512]);
      GLOAD_LDS16(Bgh + (size_t)(j * 32 + crow) * 2048 + k0 + ccol,
                  &Bs[j * 2048 + wave * 512]);
    }
    __syncthreads();
#pragma unroll
    for (int ks = 0; ks < 2; ++ks) {
      short8 af[4], bfr[4];
#pragma unroll
      for (int mi = 0; mi < 4; mi++)
        af[mi] = *(const short8*)(&As[(wm + mi * 16 + l15) * 64 + ks * 32 + l4 * 8]);
#pragma unroll
      for (int ni = 0; ni < 4; ni++)
        bfr[ni] = *(const short8*)(&Bs[(wn + ni * 16 + l15) * 64 + ks * 32 + l4 * 8]);
#pragma unroll
      for (int mi = 0; mi < 4; mi++)
#pragma unroll
        for (int ni = 0; ni < 4; ni++)
          acc[mi][ni] = __builtin_amdgcn_mfma_f32_16x16x32_bf16(af[mi], bfr[ni], acc[mi][ni], 0, 0, 0);
    }
  }
#pragma unroll
  for (int mi = 0; mi < 4; mi++)
#pragma unroll
    for (int ni = 0; ni < 4; ni++)
#pragma unroll
      for (int r = 0; r < 4; r++) {
        const int m = m0 + wm + mi * 16 + l4 * 4 + r;
        const int n = n0 + wn + ni * 16 + l15;
        C[(size_t)m * 2048 + n] = acc[mi][ni][r];
      }
}

// ---------- Fallback GEMMs (round-6 proven): B from f32 weights.

__global__ __launch_bounds__(256, 2)
void qkv_gemm_f32(const unsigned short* __restrict__ xb,
                  const float* __restrict__ Wq, const float* __restrict__ Wk,
                  const float* __restrict__ Wv, const float* __restrict__ cosb,
                  const float* __restrict__ sinb,
                  unsigned short* __restrict__ Qb, unsigned short* __restrict__ Kb,
                  unsigned short* __restrict__ Vtb) {
  __shared__ __align__(16) unsigned short As[128 * 64];
  __shared__ __align__(16) unsigned short Bs[128 * 72];
  const int t = threadIdx.x;
  const int wave = t >> 6, lane = t & 63;
  const int l15 = lane & 15, l4 = lane >> 4;
  const int wm = (wave >> 1) * 64, wn = (wave & 1) * 64;
  const int m0 = blockIdx.y * 128, n0 = blockIdx.x * 128;
  const int crow = t >> 3, ccol = (t & 7) * 8;
  const unsigned short* Ag = xb + (size_t)m0 * 2048;

  const float* Bg; int ntype;
  if (n0 < 2048)      { Bg = Wq + (size_t)n0 * 2048;          ntype = 0; }
  else if (n0 < 3072) { Bg = Wk + (size_t)(n0 - 2048) * 2048; ntype = 1; }
  else                { Bg = Wv + (size_t)(n0 - 3072) * 2048; ntype = 2; }

  const f32x4 fzero = {0.f, 0.f, 0.f, 0.f};
  f32x4 acc[4][4];
#pragma unroll
  for (int i = 0; i < 4; i++)
#pragma unroll
    for (int j = 0; j < 4; j++) acc[i][j] = fzero;

  float4 rbf[4][2];
#pragma unroll
  for (int i = 0; i < 4; i++) {
    rbf[i][0] = *(const float4*)(Bg + (size_t)(crow + 32 * i) * 2048 + ccol);
    rbf[i][1] = *(const float4*)(Bg + (size_t)(crow + 32 * i) * 2048 + ccol + 4);
  }
  for (int kt = 0; kt < 32; ++kt) {
    const int k0 = kt << 6;
    __syncthreads();
#pragma unroll
    for (int j = 0; j < 4; j++)
      GLOAD_LDS16(Ag + (size_t)(j * 32 + crow) * 2048 + k0 + ccol,
                  &As[j * 2048 + wave * 512]);
#pragma unroll
    for (int i = 0; i < 4; i++)
      *(short8*)(&Bs[(crow + 32 * i) * 72 + ccol]) = cvt8(rbf[i][0], rbf[i][1]);
    __syncthreads();
    if (kt + 1 < 32) {
      const int kn = k0 + 64;
#pragma unroll
      for (int i = 0; i < 4; i++) {
        rbf[i][0] = *(const float4*)(Bg + (size_t)(crow + 32 * i) * 2048 + kn + ccol);
        rbf[i][1] = *(const float4*)(Bg + (size_t)(crow + 32 * i) * 2048 + kn + ccol + 4);
      }
    }
#pragma unroll
    for (int ks = 0; ks < 2; ++ks) {
      short8 af[4], bfr[4];
#pragma unroll
      for (int mi = 0; mi < 4; mi++)
        af[mi] = *(const short8*)(&As[(wm + mi * 16 + l15) * 64 + ks * 32 + l4 * 8]);
#pragma unroll
      for (int ni = 0; ni < 4; ni++)
        bfr[ni] = *(const short8*)(&Bs[(wn + ni * 16 + l15) * 72 + ks * 32 + l4 * 8]);
#pragma unroll
      for (int mi = 0; mi < 4; mi++)
#pragma unroll
        for (int ni = 0; ni < 4; ni++)
          acc[mi][ni] = __builtin_amdgcn_mfma_f32_16x16x32_bf16(af[mi], bfr[ni], acc[mi][ni], 0, 0, 0);
    }
  }
#pragma unroll
  for (int mi = 0; mi < 4; mi++)
#pragma unroll
    for (int ni = 0; ni < 4; ni++)
#pragma unroll
      for (int r = 0; r < 4; r++) {
        const int m = m0 + wm + mi * 16 + l4 * 4 + r;
        const int n = n0 + wn + ni * 16 + l15;
        float fv = acc[mi][ni][r];
        if (ntype < 2) {
          const int s = m & 2047;
          const int j = (n & 63) >> 1;
          const float c = cosb[s * 32 + j];
          const float sn = sinb[s * 32 + j];
          const float p = __shfl_xor(fv, 1);
          fv = (n & 1) ? (p * sn + fv * c) : (fv * c - p * sn);
        }
        if (ntype == 0)
          Qb[(size_t)m * 2048 + n] = f2bf(fv);
        else if (ntype == 1)
          Kb[(size_t)m * 1024 + (n - 2048)] = f2bf(fv);
        else
          Vtb[((size_t)((m >> 11) * 1024 + (n - 3072))) * 2048 + (m & 2047)] = f2bf(fv);
      }
}

__global__ __launch_bounds__(256, 2)
void o_gemm_f32(const unsigned short* __restrict__ Ab, const float* __restrict__ Wo,
                float* __restrict__ C) {
  __shared__ __align__(16) unsigned short As[128 * 64];
  __shared__ __align__(16) unsigned short Bs[128 * 72];
  const int t = threadIdx.x;
  const int wave = t >> 6, lane = t & 63;
  const int l15 = lane & 15, l4 = lane >> 4;
  const int wm = (wave >> 1) * 64, wn = (wave & 1) * 64;
  const int m0 = blockIdx.y * 128, n0 = blockIdx.x * 128;
  const int crow = t >> 3, ccol = (t & 7) * 8;
  const unsigned short* Ag = Ab + (size_t)m0 * 2048;
  const float* Bg = Wo + (size_t)n0 * 2048;

  const f32x4 fzero = {0.f, 0.f, 0.f, 0.f};
  f32x4 acc[4][4];
#pragma unroll
  for (int i = 0; i < 4; i++)
#pragma unroll
    for (int j = 0; j < 4; j++) acc[i][j] = fzero;

  float4 rbf[4][2];
#pragma unroll
  for (int i = 0; i < 4; i++) {
    rbf[i][0] = *(const float4*)(Bg + (size_t)(crow + 32 * i) * 2048 + ccol);
    rbf[i][1] = *(const float4*)(Bg + (size_t)(crow + 32 * i) * 2048 + ccol + 4);
  }
  for (int kt = 0; kt < 32; ++kt) {
    const int k0 = kt << 6;
    __syncthreads();
#pragma unroll
    for (int j = 0; j < 4; j++)
      GLOAD_LDS16(Ag + (size_t)(j * 32 + crow) * 2048 + k0 + ccol,
                  &As[j * 2048 + wave * 512]);
#pragma unroll
    for (int i = 0; i < 4; i++)
      *(short8*)(&Bs[(crow + 32 * i) * 72 + ccol]) = cvt8(rbf[i][0], rbf[i][1]);
    __syncthreads();
    if (kt + 1 < 32) {
      const int kn = k0 + 64;
#pragma unroll
      for (int i = 0; i < 4; i++) {
        rbf[i][0] = *(const float4*)(Bg + (size_t)(crow + 32 * i) * 2048 + kn + ccol);
        rbf[i][1] = *(const float4*)(Bg + (size_t)(crow + 32 * i) * 2048 + kn + ccol + 4);
      }
    }
#pragma unroll
    for (int ks = 0; ks < 2; ++ks) {
      short8 af[4], bfr[4];
#pragma unroll
      for (int mi = 0; mi < 4; mi++)
        af[mi] = *(const short8*)(&As[(wm + mi * 16 + l15) * 64 + ks * 32 + l4 * 8]);
#pragma unroll
      for (int ni = 0; ni < 4; ni++)
        bfr[ni] = *(const short8*)(&Bs[(wn + ni * 16 + l15) * 72 + ks * 32 + l4 * 8]);
#pragma unroll
      for (int mi = 0; mi < 4; mi++)
#pragma unroll
        for (int ni = 0; ni < 4; ni++)
          acc[mi][ni] = __builtin_amdgcn_mfma_f32_16x16x32_bf16(af[mi], bfr[ni], acc[mi][ni], 0, 0, 0);
    }
  }
#pragma unroll
  for (int mi = 0; mi < 4; mi++)
#pragma unroll
    for (int ni = 0; ni < 4; ni++)
#pragma unroll
      for (int r = 0; r < 4; r++) {
        const int m = m0 + wm + mi * 16 + l4 * 4 + r;
        const int n = n0 + wn + ni * 16 + l15;
        C[(size_t)m * 2048 + n] = acc[mi][ni][r];
      }
}

// ---------- Fused differential flash attention, fixed-offset softmax.
// P = exp(s*0.125 - 16); ratios exact, no online max/rescale. Row-sums l via
// an extra "ones-column" MFMA (B[k][0]=1) -> accL; epilogue broadcasts col 0.
__global__ __launch_bounds__(256, 2)
void attn_kernel(const unsigned short* __restrict__ Q,
                 const unsigned short* __restrict__ Kb,
                 const unsigned short* __restrict__ Vt,
                 unsigned short* __restrict__ Ab,
                 const float* __restrict__ lq1,
                 const float* __restrict__ lk1,
                 const float* __restrict__ lq2,
                 const float* __restrict__ lk2,
                 const float* __restrict__ wsub) {
  const int pi = blockIdx.x;                 // 0..15
  const int bh = blockIdx.y;                 // b*16 + h
  const int b = bh >> 4, h = bh & 15, hk = h >> 1;
  __shared__ __align__(16) unsigned short Ks[2][64 * 72];
  __shared__ __align__(16) unsigned short Vs[128 * 72];
  __shared__ __align__(16) unsigned short Ps[2][64 * 72];
  const int t = threadIdx.x;
  const int wave = t >> 6, lane = t & 63;
  const int l15 = lane & 15, l4 = lane >> 4;
  const int crow = t >> 3, ccol = (t & 7) * 8;

  float s1 = 0.f, s2 = 0.f;
  for (int i = 0; i < 64; i++) {
    s1 += lq1[i] * lk1[i];
    s2 += lq2[i] * lk2[i];
  }
  const float lam = __expf(s1) - __expf(s2) + LAMBDA_INIT;

  float wv[8];
#pragma unroll
  for (int nt = 0; nt < 8; nt++) wv[nt] = wsub[nt * 16 + l15];

  // ones B-fragment: B[k][n] = (n==0) ? 1 : 0  (bf16 1.0 = 0x3F80)
  short8 onesf;
#pragma unroll
  for (int j = 0; j < 8; j++) onesf[j] = (l15 == 0) ? (short)0x3F80 : (short)0;

  const f32x4 fzero = {0.f, 0.f, 0.f, 0.f};
  const unsigned short* Kgb = Kb + ((size_t)(b * 2048)) * 1024 + 2 * hk * 64;
  const unsigned short* Vgb = Vt + ((size_t)((b * 8 + hk) * 128)) * 2048;

  for (int half = 0; half < 2; ++half) {
    const int qi = half ? (31 - pi) : pi;
    const int q0 = qi * 64;

    __syncthreads();
#pragma unroll
    for (int c = 0; c < 2; c++) {
      const unsigned short* Qg = Q + ((size_t)(b * 2048 + q0)) * 2048 + (2 * h + c) * 64;
#pragma unroll
      for (int i = 0; i < 2; i++) {
        const int row = crow + 32 * i;
        *(int4*)(&Ps[c][row * 72 + ccol]) = *(const int4*)(Qg + (size_t)row * 2048 + ccol);
      }
    }
    __syncthreads();
    short8 qf[2][2];
#pragma unroll
    for (int c = 0; c < 2; c++)
#pragma unroll
      for (int ks = 0; ks < 2; ks++)
        qf[c][ks] = *(const short8*)(&Ps[c][(wave * 16 + l15) * 72 + ks * 32 + l4 * 8]);

    f32x4 accO[2][8], accL[2];
#pragma unroll
    for (int c = 0; c < 2; c++) {
      accL[c] = fzero;
#pragma unroll
      for (int nt = 0; nt < 8; nt++) accO[c][nt] = fzero;
    }

    int4 rk[2][2], rv[4];
#pragma unroll
    for (int c = 0; c < 2; c++)
#pragma unroll
      for (int i = 0; i < 2; i++)
        rk[c][i] = *(const int4*)(Kgb + (size_t)(crow + 32 * i) * 1024 + c * 64 + ccol);
#pragma unroll
    for (int i = 0; i < 4; i++)
      rv[i] = *(const int4*)(Vgb + (size_t)(crow + 32 * i) * 2048 + ccol);

    for (int kt = 0; kt <= qi; ++kt) {
      const int k0 = kt * 64;
      __syncthreads();
#pragma unroll
      for (int c = 0; c < 2; c++)
#pragma unroll
        for (int i = 0; i < 2; i++)
          *(int4*)(&Ks[c][(crow + 32 * i) * 72 + ccol]) = rk[c][i];
#pragma unroll
      for (int i = 0; i < 4; i++)
        *(int4*)(&Vs[(crow + 32 * i) * 72 + ccol]) = rv[i];
      __syncthreads();
      if (kt < qi) {
        const int kn = k0 + 64;
#pragma unroll
        for (int c = 0; c < 2; c++)
#pragma unroll
          for (int i = 0; i < 2; i++)
            rk[c][i] = *(const int4*)(Kgb + (size_t)(kn + crow + 32 * i) * 1024 + c * 64 + ccol);
#pragma unroll
        for (int i = 0; i < 4; i++)
          rv[i] = *(const int4*)(Vgb + (size_t)(crow + 32 * i) * 2048 + kn + ccol);
      }
      const bool diag = (kt == qi);
#pragma unroll
      for (int c = 0; c < 2; c++) {
        f32x4 sc[4];
#pragma unroll
        for (int ct = 0; ct < 4; ct++) {
          const short8 kb0 = *(const short8*)(&Ks[c][(ct * 16 + l15) * 72 + 0 + l4 * 8]);
          const short8 kb1 = *(const short8*)(&Ks[c][(ct * 16 + l15) * 72 + 32 + l4 * 8]);
          f32x4 z = fzero;
          z = __builtin_amdgcn_mfma_f32_16x16x32_bf16(qf[c][0], kb0, z, 0, 0, 0);
          z = __builtin_amdgcn_mfma_f32_16x16x32_bf16(qf[c][1], kb1, z, 0, 0, 0);
          sc[ct] = z;
        }
#pragma unroll
        for (int r = 0; r < 4; r++) {
          const int qrow = q0 + wave * 16 + l4 * 4 + r;
#pragma unroll
          for (int ct = 0; ct < 4; ct++) {
            float e = __expf(fmaf(sc[ct][r], 0.125f, -16.0f));
            if (diag && (k0 + ct * 16 + l15) > qrow) e = 0.f;
            Ps[c][(wave * 16 + l4 * 4 + r) * 72 + ct * 16 + l15] = f2bf(e);
          }
        }
      }
      // Wave-local P round-trip (wave w writes/reads rows [16w,16w+16)).
      short8 pf[2][2];
#pragma unroll
      for (int c = 0; c < 2; c++)
#pragma unroll
        for (int ks = 0; ks < 2; ks++)
          pf[c][ks] = *(const short8*)(&Ps[c][(wave * 16 + l15) * 72 + ks * 32 + l4 * 8]);
#pragma unroll
      for (int nt = 0; nt < 8; nt++) {
        const short8 v0 = *(const short8*)(&Vs[(nt * 16 + l15) * 72 + 0 + l4 * 8]);
        const short8 v1 = *(const short8*)(&Vs[(nt * 16 + l15) * 72 + 32 + l4 * 8]);
        accO[0][nt] = __builtin_amdgcn_mfma_f32_16x16x32_bf16(pf[0][0], v0, accO[0][nt], 0, 0, 0);
        accO[0][nt] = __builtin_amdgcn_mfma_f32_16x16x32_bf16(pf[0][1], v1, accO[0][nt], 0, 0, 0);
        accO[1][nt] = __builtin_amdgcn_mfma_f32_16x16x32_bf16(pf[1][0], v0, accO[1][nt], 0, 0, 0);
        accO[1][nt] = __builtin_amdgcn_mfma_f32_16x16x32_bf16(pf[1][1], v1, accO[1][nt], 0, 0, 0);
      }
      accL[0] = __builtin_amdgcn_mfma_f32_16x16x32_bf16(pf[0][0], onesf, accL[0], 0, 0, 0);
      accL[0] = __builtin_amdgcn_mfma_f32_16x16x32_bf16(pf[0][1], onesf, accL[0], 0, 0, 0);
      accL[1] = __builtin_amdgcn_mfma_f32_16x16x32_bf16(pf[1][0], onesf, accL[1], 0, 0, 0);
      accL[1] = __builtin_amdgcn_mfma_f32_16x16x32_bf16(pf[1][1], onesf, accL[1], 0, 0, 0);
    }

    // Epilogue: o1 - lam*o2, RMS-norm over 128, * subln_w * (1 - lambda_init).
#pragma unroll
    for (int r = 0; r < 4; r++) {
      const float l1 = __shfl(accL[0][r], lane & 48);
      const float l2 = __shfl(accL[1][r], lane & 48);
      const float i1 = 1.f / fmaxf(l1, 1e-30f);
      const float i2 = lam / fmaxf(l2, 1e-30f);
      float av[8], ss = 0.f;
#pragma unroll
      for (int nt = 0; nt < 8; nt++) {
        const float a = accO[0][nt][r] * i1 - accO[1][nt][r] * i2;
        av[nt] = a;
        ss += a * a;
      }
#pragma unroll
      for (int off = 1; off < 16; off <<= 1) ss += __shfl_xor(ss, off, 16);
      const float sca = rsqrtf(ss * (1.f / 128.f) + 1e-5f) * (1.f - LAMBDA_INIT);
      const int qrow = q0 + wave * 16 + l4 * 4 + r;
      unsigned short* Ao = Ab + ((size_t)(b * 2048 + qrow)) * 2048 + h * 128;
#pragma unroll
      for (int nt = 0; nt < 8; nt++)
        Ao[nt * 16 + l15] = f2bf(av[nt] * sca * wv[nt]);
    }
  }
}

extern "C" void kernel_launch(void* const* d_in, const int* in_sizes, int n_in,
                              void* d_out, int out_size, void* d_ws, size_t ws_size,
                              hipStream_t stream) {
  const float* x    = (const float*)d_in[0];
  const float* cosb = (const float*)d_in[1];
  const float* sinb = (const float*)d_in[2];
  const float* Wq   = (const float*)d_in[3];
  const float* Wk   = (const float*)d_in[4];
  const float* Wv   = (const float*)d_in[5];
  const float* Wo   = (const float*)d_in[6];
  const float* lq1  = (const float*)d_in[7];
  const float* lk1  = (const float*)d_in[8];
  const float* lq2  = (const float*)d_in[9];
  const float* lk2  = (const float*)d_in[10];
  const float* wsub = (const float*)d_in[11];
  float* out = (float*)d_out;

  // ws layout (fast, ws>=40MiB): [0,16) xb -> later A | [16,24) Wqb | [24,28) Wkb
  //   | [28,32) Wvb | [32,40) Wob.  Fallback (ws>=16MiB): [0,16) xb -> A.
  // d_out (32 MiB f32) temporarily hosts bf16 K(8) | Vt(8) | Q(16); O-GEMM
  // overwrites d_out with f32 C (K/Vt/Q dead by then).
  unsigned short* XA  = (unsigned short*)d_ws;
  unsigned short* Kb  = (unsigned short*)d_out;
  unsigned short* Vtb = Kb + (size_t)4096 * 1024;
  unsigned short* Qb  = Vtb + (size_t)2 * 1024 * 2048;

  dim3 blk(256);
  if (ws_size >= (size_t)41943040) {
    unsigned short* Wqb = XA + 8388608;
    unsigned short* Wkb = XA + 12582912;
    unsigned short* Wvb = XA + 14680064;
    unsigned short* Wob = XA + 16777216;
    conv_all<<<10240, blk, 0, stream>>>(x, Wq, Wk, Wv, Wo, XA);
    qkv_bb<<<dim3(32, 32), blk, 0, stream>>>(XA, Wqb, Wkb, Wvb, cosb, sinb, Qb, Kb, Vtb);
    attn_kernel<<<dim3(16, 32), blk, 0, stream>>>(Qb, Kb, Vtb, XA, lq1, lk1, lq2, lk2, wsub);
    o_bb<<<dim3(16, 32), blk, 0, stream>>>(XA, Wob, out);
  } else {
    conv_bf16<<<4096, blk, 0, stream>>>(x, XA, 1048576);
    qkv_gemm_f32<<<dim3(32, 32), blk, 0, stream>>>(XA, Wq, Wk, Wv, cosb, sinb, Qb, Kb, Vtb);
    attn_kernel<<<dim3(16, 32), blk, 0, stream>>>(Qb, Kb, Vtb, XA, lq1, lk1, lq2, lk2, wsub);
    o_gemm_f32<<<dim3(16, 32), blk, 0, stream>>>(XA, Wo, out);
  }
}